// Round 6
// baseline (209.774 us; speedup 1.0000x reference)
//
#include <hip/hip_runtime.h>

#define HW 2304
#define W48 48
#define RS_STRIDE 50       // Rs row stride in floats
#define RS_ROWS 52         // rows 0..51 hold R((r-2) mod 48)
#define RS_SIZE (RS_ROWS * RS_STRIDE)

// ---------------------------------------------------------------------------
// prep: build rec_ext (float4: c0,c1,c2,walls) for all 16 timesteps,
//       build cur0 (frame 0 + walls), copy frame 0 (3ch) to d_out.
// ---------------------------------------------------------------------------
__global__ __launch_bounds__(256) void prep_kernel(
    const float* __restrict__ x, const float* __restrict__ rec,
    const float* __restrict__ walls,
    float4* __restrict__ rec4, float4* __restrict__ cur0,
    float* __restrict__ dout)
{
    int id = blockIdx.x * 256 + threadIdx.x;
    if (id < 16 * HW) {
        int t = id / HW, p = id % HW;
        rec4[id] = make_float4(rec[(t * 3 + 0) * HW + p],
                               rec[(t * 3 + 1) * HW + p],
                               rec[(t * 3 + 2) * HW + p],
                               walls[p]);
    }
    if (id < HW) {
        cur0[id] = make_float4(x[0 * HW + id], x[1 * HW + id], x[2 * HW + id],
                               walls[id]);
    }
    if (id < 3 * HW) {
        dout[id] = x[id];  // frame 0, channels 0..2
    }
}

// ---------------------------------------------------------------------------
// dist v6: block=(t,sy), 720 blocks x 384 threads (6 waves).
// v5 structure (LDS = Rs exchange only; rec from L2 into 8 NAMED ring regs)
// with two fixes per r5 counters:
//  - __launch_bounds__(384,2): r5's (384,4) forced VGPR=64 -> scratch spill
//    (WRITE_SIZE 13->24 MB). Cap ~170 removes the spill.
//  - 2 sx fused per barrier phase (STEP2): 48 -> 24 barriers, 2 independent
//    DIFF/R/read chains per phase for ILP. 4 Rs buffers (pair parity) keep
//    the write-after-read hazard barrier-separated.
// Per-sx F/R/D expressions and summation order bit-identical to r4/r5.
// ---------------------------------------------------------------------------
__global__ __launch_bounds__(384, 2) void dist_kernel(
    const float4* __restrict__ rec4, const float4* __restrict__ cur4,
    unsigned long long* __restrict__ best)
{
    __shared__ float Rs[4 * RS_SIZE];      // 41600 B

    const int tid = threadIdx.x;
    const int b   = blockIdx.x;
    const int sy  = b % W48;
    const int t   = b / W48;

    // AB ownership
    const int yA = tid >> 3;          // 0..47
    const int cA = tid & 7;           // 0..7
    const int x0 = 6 * cA;            // 0..42
    int ryA = yA + sy; if (ryA >= W48) ryA -= W48;

    // C ownership
    const int xC = tid % W48;
    const int y0 = 6 * (tid / W48);

    // bpermute byte-addresses: circular left/right neighbor within row-of-8
    const int lane  = tid & 63;
    const int addrL = ((lane & ~7) | ((cA + 7) & 7)) << 2;
    const int addrR = ((lane & ~7) | ((cA + 1) & 7)) << 2;

    unsigned int mb[6];
#pragma unroll
    for (int i = 0; i < 6; i++) {
        int ry = y0 + i + sy; if (ry >= W48) ry -= W48;
        mb[i] = (unsigned int)(t * HW + ry * W48);
    }

    // fixed cur window: cw_j = cur(yA, x0+j)   (x0+5 <= 47, no wrap)
    const float4* curRow = cur4 + yA * W48 + x0;
    const float4 cw0 = curRow[0];
    const float4 cw1 = curRow[1];
    const float4 cw2 = curRow[2];
    const float4 cw3 = curRow[3];
    const float4 cw4 = curRow[4];
    const float4 cw5 = curRow[5];

    // rec row base for this thread (L2-resident)
    const float4* recRow = rec4 + t * HW + ryA * W48;

    // ring init: slot j holds rec col (x0+j)%48
    float4 s0 = recRow[x0 + 0];
    float4 s1 = recRow[x0 + 1];
    float4 s2 = recRow[x0 + 2];
    float4 s3 = recRow[x0 + 3];
    float4 s4 = recRow[x0 + 4];
    float4 s5 = recRow[x0 + 5];
    float4 s6, s7;
    {
        int c6 = x0 + 6; if (c6 >= W48) c6 -= W48;
        int c7 = x0 + 7; if (c7 >= W48) c7 -= W48;
        s6 = recRow[c6];
        s7 = recRow[c7];
    }

    int nc = x0 + 8; if (nc >= W48) nc -= W48;  // next col to fetch
    int rx = xC;                                 // candidate col (xC+sx)%48

    unsigned long long bst[6];
#pragma unroll
    for (int i = 0; i < 6; i++) bst[i] = ~0ULL;

#define DIFF(D, C, Wv) do {                                                 \
        float d0 = (C).x - (Wv).x, d1 = (C).y - (Wv).y,                     \
              d2 = (C).z - (Wv).z, d3 = (C).w - (Wv).w;                     \
        D = d0 * d0 + d1 * d1 + d2 * d2 + d3 * d3;                          \
    } while (0)

#define ROWSUM(RsB)                                                         \
        {                                                                   \
            float* rw = &(RsB)[(yA + 2) * RS_STRIDE + x0];                  \
            *(float2*)&rw[0] = make_float2(R0, R1);                         \
            *(float2*)&rw[2] = make_float2(R2, R3);                         \
            *(float2*)&rw[4] = make_float2(R4, R5);                         \
        }                                                                   \
        if (yA < 2) {                                                       \
            float* rw = &(RsB)[(yA + 50) * RS_STRIDE + x0];                 \
            *(float2*)&rw[0] = make_float2(R0, R1);                         \
            *(float2*)&rw[2] = make_float2(R2, R3);                         \
            *(float2*)&rw[4] = make_float2(R4, R5);                         \
        }                                                                   \
        if (yA >= 46) {                                                     \
            float* rw = &(RsB)[(yA - 46) * RS_STRIDE + x0];                 \
            *(float2*)&rw[0] = make_float2(R0, R1);                         \
            *(float2*)&rw[2] = make_float2(R2, R3);                         \
            *(float2*)&rw[4] = make_float2(R4, R5);                         \
        }

#define COLMIN(RsB, RX)                                                     \
        {                                                                   \
            const float* rp = &(RsB)[y0 * RS_STRIDE + xC];                  \
            float rv[10];                                                   \
            _Pragma("unroll")                                               \
            for (int j = 0; j < 10; j++) rv[j] = rp[j * RS_STRIDE];         \
            _Pragma("unroll")                                               \
            for (int i = 0; i < 6; i++) {                                   \
                float d = rv[i] + rv[i + 1] + rv[i + 2] + rv[i + 3] +       \
                          rv[i + 4];                                        \
                unsigned long long pk =                                     \
                    ((unsigned long long)__float_as_uint(d) << 32) |        \
                    (mb[i] + (RX));                                         \
                bst[i] = pk < bst[i] ? pk : bst[i];                         \
            }                                                               \
        }

// STEP2: process sx pair (even uses A0..A5, odd uses A1..A6); refill A0,A1.
#define STEP2(P, A0, A1, A2, A3, A4, A5, A6) do {                           \
        float* RsE = &Rs[(2 * (P)) * RS_SIZE];                              \
        float* RsO = &Rs[(2 * (P) + 1) * RS_SIZE];                          \
        {                                                                   \
            float F0, F1, F2, F3, F4, F5;                                   \
            DIFF(F0, cw0, A0); DIFF(F1, cw1, A1); DIFF(F2, cw2, A2);        \
            DIFF(F3, cw3, A3); DIFF(F4, cw4, A4); DIFF(F5, cw5, A5);        \
            float Fm2 = __int_as_float(                                     \
                __builtin_amdgcn_ds_bpermute(addrL, __float_as_int(F4)));   \
            float Fm1 = __int_as_float(                                     \
                __builtin_amdgcn_ds_bpermute(addrL, __float_as_int(F5)));   \
            float F6  = __int_as_float(                                     \
                __builtin_amdgcn_ds_bpermute(addrR, __float_as_int(F0)));   \
            float F7  = __int_as_float(                                     \
                __builtin_amdgcn_ds_bpermute(addrR, __float_as_int(F1)));   \
            float R0 = Fm2 + Fm1 + F0 + F1 + F2;                            \
            float R1 = Fm1 + F0 + F1 + F2 + F3;                             \
            float R2 = F0 + F1 + F2 + F3 + F4;                              \
            float R3 = F1 + F2 + F3 + F4 + F5;                              \
            float R4 = F2 + F3 + F4 + F5 + F6;                              \
            float R5 = F3 + F4 + F5 + F6 + F7;                              \
            ROWSUM(RsE)                                                     \
        }                                                                   \
        {                                                                   \
            float F0, F1, F2, F3, F4, F5;                                   \
            DIFF(F0, cw0, A1); DIFF(F1, cw1, A2); DIFF(F2, cw2, A3);        \
            DIFF(F3, cw3, A4); DIFF(F4, cw4, A5); DIFF(F5, cw5, A6);        \
            float Fm2 = __int_as_float(                                     \
                __builtin_amdgcn_ds_bpermute(addrL, __float_as_int(F4)));   \
            float Fm1 = __int_as_float(                                     \
                __builtin_amdgcn_ds_bpermute(addrL, __float_as_int(F5)));   \
            float F6  = __int_as_float(                                     \
                __builtin_amdgcn_ds_bpermute(addrR, __float_as_int(F0)));   \
            float F7  = __int_as_float(                                     \
                __builtin_amdgcn_ds_bpermute(addrR, __float_as_int(F1)));   \
            float R0 = Fm2 + Fm1 + F0 + F1 + F2;                            \
            float R1 = Fm1 + F0 + F1 + F2 + F3;                             \
            float R2 = F0 + F1 + F2 + F3 + F4;                              \
            float R3 = F1 + F2 + F3 + F4 + F5;                              \
            float R4 = F2 + F3 + F4 + F5 + F6;                              \
            float R5 = F3 + F4 + F5 + F6 + F7;                              \
            ROWSUM(RsO)                                                     \
        }                                                                   \
        A0 = recRow[nc];                                                    \
        {                                                                   \
            int nc1 = nc + 1; if (nc1 >= W48) nc1 -= W48;                   \
            A1 = recRow[nc1];                                               \
        }                                                                   \
        nc += 2; if (nc >= W48) nc -= W48;                                  \
        __syncthreads();                                                    \
        COLMIN(RsE, rx)                                                     \
        {                                                                   \
            int rx1 = rx + 1; if (rx1 >= W48) rx1 -= W48;                   \
            COLMIN(RsO, rx1)                                                \
        }                                                                   \
        rx += 2; if (rx >= W48) rx -= W48;                                  \
    } while (0)

    for (int so = 0; so < 6; so++) {
        STEP2(0, s0, s1, s2, s3, s4, s5, s6);
        STEP2(1, s2, s3, s4, s5, s6, s7, s0);
        STEP2(0, s4, s5, s6, s7, s0, s1, s2);
        STEP2(1, s6, s7, s0, s1, s2, s3, s4);
    }
#undef STEP2
#undef COLMIN
#undef ROWSUM
#undef DIFF

#pragma unroll
    for (int i = 0; i < 6; i++)
        atomicMin(&best[(y0 + i) * W48 + xC], bst[i]);
}

// ---------------------------------------------------------------------------
// gather: decode best[p]; gather center pixel of (t+1) patch; write output
// frame + next carry + per-element sq-error.
// ---------------------------------------------------------------------------
__global__ __launch_bounds__(256) void gather_kernel(
    const unsigned long long* __restrict__ best,
    const float4* __restrict__ rec4, const float* __restrict__ x,
    const float* __restrict__ walls,
    float4* __restrict__ curnext, float* __restrict__ dout,
    float* __restrict__ err, int step)
{
    int p = blockIdx.x * 256 + threadIdx.x;
    if (p >= HW) return;
    unsigned int m = (unsigned int)best[p];
    int t = m / HW, q = m % HW;
    float4 v = rec4[(t + 1) * HW + q];
    curnext[p] = v;
    dout[(step + 1) * 3 * HW + 0 * HW + p] = v.x;
    dout[(step + 1) * 3 * HW + 1 * HW + p] = v.y;
    dout[(step + 1) * 3 * HW + 2 * HW + p] = v.z;
    float t0 = x[((step + 1) * 3 + 0) * HW + p];
    float t1 = x[((step + 1) * 3 + 1) * HW + p];
    float t2 = x[((step + 1) * 3 + 2) * HW + p];
    float t3 = walls[p];
    float e = (v.x - t0) * (v.x - t0) + (v.y - t1) * (v.y - t1) +
              (v.z - t2) * (v.z - t2) + (v.w - t3) * (v.w - t3);
    err[step * HW + p] = e;
}

// ---------------------------------------------------------------------------
// loss: deterministic reduction; loss = total / 18432.
// ---------------------------------------------------------------------------
__global__ __launch_bounds__(256) void loss_kernel(
    const float* __restrict__ err, float* __restrict__ dout)
{
    __shared__ float ssum[256];
    float s = 0.f;
    for (int i = threadIdx.x; i < 2 * HW; i += 256) s += err[i];
    ssum[threadIdx.x] = s;
    __syncthreads();
    for (int w = 128; w > 0; w >>= 1) {
        if (threadIdx.x < w) ssum[threadIdx.x] += ssum[threadIdx.x + w];
        __syncthreads();
    }
    if (threadIdx.x == 0) dout[9 * HW] = ssum[0] / 18432.0f;
}

extern "C" void kernel_launch(void* const* d_in, const int* in_sizes, int n_in,
                              void* d_out, int out_size, void* d_ws,
                              size_t ws_size, hipStream_t stream)
{
    const float* x     = (const float*)d_in[0];
    const float* rec   = (const float*)d_in[1];
    const float* walls = (const float*)d_in[2];
    float* dout = (float*)d_out;

    char* ws = (char*)d_ws;
    float4* rec4 = (float4*)ws;                               // 589824 B
    float4* curb = (float4*)(ws + 589824);                    // 110592 B
    float*  err  = (float*)(ws + 589824 + 110592);            //  18432 B
    unsigned long long* best =
        (unsigned long long*)(ws + 589824 + 110592 + 18432);  //  18432 B

    prep_kernel<<<144, 256, 0, stream>>>(x, rec, walls, rec4, curb, dout);
    for (int step = 0; step < 2; step++) {
        hipMemsetAsync(best, 0xFF, (size_t)HW * 8, stream);
        dist_kernel<<<15 * W48, 384, 0, stream>>>(rec4, curb + step * HW, best);
        gather_kernel<<<9, 256, 0, stream>>>(best, rec4, x, walls,
                                             curb + (step + 1) * HW, dout, err,
                                             step);
    }
    loss_kernel<<<1, 256, 0, stream>>>(err, dout);
}